// Round 1
// baseline (607.924 us; speedup 1.0000x reference)
//
#include <hip/hip_runtime.h>

// ============================================================================
// ETC layer: windowed rel-pos attention + FFN, bf16 MFMA GEMMs on gfx950
//   B=2 S=2048 D_MODEL=1024 NHEAD=16 DHEAD=64 DFF=4096 R=25 W=51 K=5
// Pipeline:
//   cvt(src,wq,wk,wv,wo,w1,w2 -> bf16), concat(bq,bk,bv)
//   qkv  = xb @ wqkv^T + bqkv            (bf16 out, 4096x3072)
//   attn = windowed softmax(q k^T + q rel^T) v   (bf16 out, 4096x1024)
//   z    = attn @ wo^T + bo              (fp32)
//   x1   = LN(src + z)*g1+b1             (bf16 out)
//   ff1  = relu(x1 @ w1^T + b1)          (bf16 out, 4096x4096)
//   ff2  = ff1 @ w2^T + b2               (fp32)
//   out  = LN(x1 + ff2)*g2+b2            (fp32)
// ============================================================================

#define D_MODEL 1024
#define SEQ     2048
#define NROWS   4096      // B*S
#define WIN     51
#define RAD     25

typedef __attribute__((ext_vector_type(8))) __bf16 bf16x8;
typedef __attribute__((ext_vector_type(4))) float  floatx4;

__device__ __forceinline__ unsigned short f2bf(float x) {
    unsigned u = __float_as_uint(x);
    unsigned r = u + 0x7fffu + ((u >> 16) & 1u);
    return (unsigned short)(r >> 16);
}
__device__ __forceinline__ float bf2f(unsigned short h) {
    return __uint_as_float(((unsigned)h) << 16);
}

// ---------------------------------------------------------------------------
// fp32 -> bf16 bulk convert (4 elems / thread)
// ---------------------------------------------------------------------------
__global__ __launch_bounds__(256) void cvt4(const float* __restrict__ in,
                                            unsigned short* __restrict__ out,
                                            int n4) {
    int i = blockIdx.x * 256 + threadIdx.x;
    if (i >= n4) return;
    float4 f = ((const float4*)in)[i];
    ushort4 u;
    u.x = f2bf(f.x); u.y = f2bf(f.y); u.z = f2bf(f.z); u.w = f2bf(f.w);
    ((ushort4*)out)[i] = u;
}

__global__ __launch_bounds__(256) void concat3(const float* __restrict__ a,
                                               const float* __restrict__ b,
                                               const float* __restrict__ c,
                                               float* __restrict__ out) {
    int i = blockIdx.x * 256 + threadIdx.x;   // 3072 total
    if (i >= 3072) return;
    float v = (i < 1024) ? a[i] : (i < 2048 ? b[i - 1024] : c[i - 2048]);
    out[i] = v;
}

// ---------------------------------------------------------------------------
// GEMM  C[M,N] = A[M,K] @ W[N,K]^T + bias   (bf16 in, fp32 acc)
// 128x128 block tile, 256 threads (4 waves), each wave a 64x64 quadrant,
// 4x4 grid of 16x16x32 bf16 MFMA per wave. BK=32 = MFMA K.
// Verified layouts (learn_hip m89/m91/m92):
//   A/B fragment: elem [m|n = lane&15][k = (lane>>4)*8 + j]
//   C/D:          col = lane&15, row = (lane>>4)*4 + reg
// ---------------------------------------------------------------------------
#define BM 128
#define BN 128
#define BK 32

__global__ __launch_bounds__(256, 2)
void gemm_bt(const unsigned short* __restrict__ A,   // M x K   bf16
             const unsigned short* __restrict__ Wt,  // N x K   bf16
             const float* __restrict__ bias,         // N
             float* __restrict__ Cf,                 // M x ldc fp32   (or null)
             unsigned short* __restrict__ Cb,        // M x ldc bf16   (or null)
             int K, int ldc, int relu)
{
    __shared__ __attribute__((aligned(16))) unsigned short As[BM * BK];
    __shared__ __attribute__((aligned(16))) unsigned short Bs[BN * BK];

    const int tid  = threadIdx.x;
    const int lane = tid & 63;
    const int wave = tid >> 6;
    const int bm = blockIdx.y * BM;
    const int bn = blockIdx.x * BN;
    const int wm = (wave >> 1) * 64;
    const int wn = (wave & 1) * 64;

    // staging: 256 threads cover 128 rows x 32 cols in 16B chunks (x2)
    const int srow = tid >> 2;            // 0..63
    const int scol = (tid & 3) * 8;       // 0,8,16,24 (bf16 elems)
    const unsigned short* Ag0 = A  + (size_t)(bm + srow) * K + scol;
    const unsigned short* Ag1 = Ag0 + (size_t)64 * K;
    const unsigned short* Wg0 = Wt + (size_t)(bn + srow) * K + scol;
    const unsigned short* Wg1 = Wg0 + (size_t)64 * K;

    const int fm = lane & 15;
    const int fk = (lane >> 4) * 8;

    floatx4 acc[4][4] = {};

    for (int k0 = 0; k0 < K; k0 += BK) {
        uint4 a0 = *(const uint4*)(Ag0 + k0);
        uint4 a1 = *(const uint4*)(Ag1 + k0);
        uint4 b0 = *(const uint4*)(Wg0 + k0);
        uint4 b1 = *(const uint4*)(Wg1 + k0);
        __syncthreads();   // previous iter's frag reads done before overwrite
        *(uint4*)(As + srow * BK + scol)        = a0;
        *(uint4*)(As + (64 + srow) * BK + scol) = a1;
        *(uint4*)(Bs + srow * BK + scol)        = b0;
        *(uint4*)(Bs + (64 + srow) * BK + scol) = b1;
        __syncthreads();

        bf16x8 af[4], bf[4];
        #pragma unroll
        for (int i = 0; i < 4; i++)
            af[i] = *(const bf16x8*)(As + (wm + i * 16 + fm) * BK + fk);
        #pragma unroll
        for (int j = 0; j < 4; j++)
            bf[j] = *(const bf16x8*)(Bs + (wn + j * 16 + fm) * BK + fk);
        #pragma unroll
        for (int i = 0; i < 4; i++)
            #pragma unroll
            for (int j = 0; j < 4; j++)
                acc[i][j] = __builtin_amdgcn_mfma_f32_16x16x32_bf16(
                    af[i], bf[j], acc[i][j], 0, 0, 0);
    }

    const int r0 = bm + wm + (lane >> 4) * 4;
    const int c0 = bn + wn + (lane & 15);
    #pragma unroll
    for (int i = 0; i < 4; i++) {
        #pragma unroll
        for (int j = 0; j < 4; j++) {
            const int col = c0 + j * 16;
            const float bv = bias[col];
            #pragma unroll
            for (int r = 0; r < 4; r++) {
                const int row = r0 + i * 16 + r;
                float v = acc[i][j][r] + bv;
                if (relu) v = fmaxf(v, 0.0f);
                if (Cf) Cf[(size_t)row * ldc + col] = v;
                if (Cb) Cb[(size_t)row * ldc + col] = f2bf(v);
            }
        }
    }
}

// ---------------------------------------------------------------------------
// Windowed relative attention. One wave per (b,h,s); lane = head dim.
// qkv: (B*S) x 3072 bf16 rows [q | k | v]; rel: 11 x 64 fp32.
// out: (B*S) x 1024 bf16 (b,s,h,d layout, ready for wo GEMM)
// ---------------------------------------------------------------------------
__global__ __launch_bounds__(256)
void attn_win(const unsigned short* __restrict__ qkv,
              const float* __restrict__ rel,
              unsigned short* __restrict__ attnb)
{
    const int wave = threadIdx.x >> 6;
    const int lane = threadIdx.x & 63;
    const int g = blockIdx.x * 4 + wave;      // 0..65535 = ((b*16+h)*2048+s)
    const int s  = g & (SEQ - 1);
    const int bh = g >> 11;
    const int h  = bh & 15;
    const int b  = bh >> 4;
    const int base_row = b * SEQ;
    const float scale = 0.125f;               // 1/sqrt(64)

    const float qd = bf2f(qkv[(size_t)(base_row + s) * 3072 + h * 64 + lane]);

    float scores[WIN];
    #pragma unroll
    for (int w = 0; w < WIN; w++) {
        const int j  = s - RAD + w;
        const int jc = min(max(j, 0), SEQ - 1);
        float kd = bf2f(qkv[(size_t)(base_row + jc) * 3072 + 1024 + h * 64 + lane]);
        const int rid = min(max(w - RAD, -5), 5) + 5;
        kd += rel[rid * 64 + lane];
        float p = qd * kd;
        #pragma unroll
        for (int off = 32; off > 0; off >>= 1)
            p += __shfl_xor(p, off);
        scores[w] = (j >= 0 && j < SEQ) ? p * scale : -1e30f;
    }

    float mx = -1e30f;
    #pragma unroll
    for (int w = 0; w < WIN; w++) mx = fmaxf(mx, scores[w]);
    float sum = 0.0f;
    #pragma unroll
    for (int w = 0; w < WIN; w++) { scores[w] = __expf(scores[w] - mx); sum += scores[w]; }
    const float inv = 1.0f / sum;

    float out = 0.0f;
    #pragma unroll
    for (int w = 0; w < WIN; w++) {
        const int j  = s - RAD + w;
        const int jc = min(max(j, 0), SEQ - 1);
        const float vd = bf2f(qkv[(size_t)(base_row + jc) * 3072 + 2048 + h * 64 + lane]);
        out += scores[w] * vd;   // masked w have weight exactly 0
    }
    out *= inv;
    attnb[(size_t)(base_row + s) * 1024 + h * 64 + lane] = f2bf(out);
}

// ---------------------------------------------------------------------------
// Fused residual + LayerNorm. One wave per row (1024 cols, 16/lane).
// Residual input 1 is fp32 (af) OR bf16 (ab); input 2 always fp32.
// ---------------------------------------------------------------------------
__global__ __launch_bounds__(256)
void ln_fuse(const float* __restrict__ af,
             const unsigned short* __restrict__ ab,
             const float* __restrict__ bres,
             const float* __restrict__ gamma,
             const float* __restrict__ beta,
             float* __restrict__ outf,
             unsigned short* __restrict__ outb)
{
    const int wave = threadIdx.x >> 6;
    const int lane = threadIdx.x & 63;
    const int row = blockIdx.x * 4 + wave;
    const size_t base = (size_t)row * D_MODEL;

    float x[16];
    float sum = 0.0f, sq = 0.0f;
    #pragma unroll
    for (int i = 0; i < 4; i++) {
        const int c4 = lane + i * 64;      // float4 chunk within row
        float4 vb = ((const float4*)(bres + base))[c4];
        float4 va;
        if (af) {
            va = ((const float4*)(af + base))[c4];
        } else {
            ushort4 ua = ((const ushort4*)(ab + base))[c4];
            va.x = bf2f(ua.x); va.y = bf2f(ua.y); va.z = bf2f(ua.z); va.w = bf2f(ua.w);
        }
        float e0 = va.x + vb.x, e1 = va.y + vb.y, e2 = va.z + vb.z, e3 = va.w + vb.w;
        x[i*4+0] = e0; x[i*4+1] = e1; x[i*4+2] = e2; x[i*4+3] = e3;
        sum += e0 + e1 + e2 + e3;
        sq  += e0*e0 + e1*e1 + e2*e2 + e3*e3;
    }
    #pragma unroll
    for (int off = 32; off > 0; off >>= 1) {
        sum += __shfl_xor(sum, off);
        sq  += __shfl_xor(sq,  off);
    }
    const float mean = sum * (1.0f / 1024.0f);
    const float var  = sq  * (1.0f / 1024.0f) - mean * mean;
    const float rs   = rsqrtf(var + 1e-5f);

    #pragma unroll
    for (int i = 0; i < 4; i++) {
        const int c4 = lane + i * 64;
        float4 g4 = ((const float4*)gamma)[c4];
        float4 b4 = ((const float4*)beta)[c4];
        float4 o;
        o.x = (x[i*4+0] - mean) * rs * g4.x + b4.x;
        o.y = (x[i*4+1] - mean) * rs * g4.y + b4.y;
        o.z = (x[i*4+2] - mean) * rs * g4.z + b4.z;
        o.w = (x[i*4+3] - mean) * rs * g4.w + b4.w;
        if (outf) ((float4*)(outf + base))[c4] = o;
        if (outb) {
            ushort4 u;
            u.x = f2bf(o.x); u.y = f2bf(o.y); u.z = f2bf(o.z); u.w = f2bf(o.w);
            ((ushort4*)(outb + base))[c4] = u;
        }
    }
}

// ---------------------------------------------------------------------------
extern "C" void kernel_launch(void* const* d_in, const int* in_sizes, int n_in,
                              void* d_out, int out_size, void* d_ws, size_t ws_size,
                              hipStream_t stream)
{
    const float* src = (const float*)d_in[0];
    const float* wq  = (const float*)d_in[1];
    const float* bq  = (const float*)d_in[2];
    const float* wk  = (const float*)d_in[3];
    const float* bk  = (const float*)d_in[4];
    const float* wv  = (const float*)d_in[5];
    const float* bv  = (const float*)d_in[6];
    const float* wo  = (const float*)d_in[7];
    const float* bo  = (const float*)d_in[8];
    const float* rel = (const float*)d_in[9];
    const float* w1  = (const float*)d_in[10];
    const float* b1  = (const float*)d_in[11];
    const float* w2  = (const float*)d_in[12];
    const float* b2  = (const float*)d_in[13];
    const float* g1  = (const float*)d_in[14];
    const float* be1 = (const float*)d_in[15];
    const float* g2  = (const float*)d_in[16];
    const float* be2 = (const float*)d_in[17];
    float* out = (float*)d_out;

    char* ws = (char*)d_ws;
    const size_t MB = 1048576;
    // workspace layout (89 MB total, with liveness-based reuse)
    unsigned short* wqkvb = (unsigned short*)(ws + 0);        //  6 MB  3072x1024 bf16
    unsigned short* wob   = (unsigned short*)(ws + 6  * MB);  //  2 MB
    unsigned short* w1b   = (unsigned short*)(ws + 8  * MB);  //  8 MB
    unsigned short* w2b   = (unsigned short*)(ws + 16 * MB);  //  8 MB
    float*          bqkv  = (float*)         (ws + 24 * MB);  // 12 KB
    unsigned short* xb    = (unsigned short*)(ws + 25 * MB);  //  8 MB (dead after QKV gemm)
    unsigned short* attnb = (unsigned short*)(ws + 25 * MB);  //  reuse xb
    unsigned short* qkvb  = (unsigned short*)(ws + 33 * MB);  // 24 MB (dead after attn)
    unsigned short* ff1b  = (unsigned short*)(ws + 33 * MB);  // 32 MB, reuse qkvb region
    float*          z     = (float*)         (ws + 65 * MB);  // 16 MB (dead after LN1)
    float*          ff2   = (float*)         (ws + 65 * MB);  //  reuse z
    unsigned short* x1b   = (unsigned short*)(ws + 81 * MB);  //  8 MB (ends 89 MB)

    // --- bf16 conversions ---
    cvt4<<<4096, 256, 0, stream>>>(src, xb, 1048576);
    cvt4<<<1024, 256, 0, stream>>>(wq, wqkvb,           262144);
    cvt4<<<1024, 256, 0, stream>>>(wk, wqkvb + 1048576, 262144);
    cvt4<<<1024, 256, 0, stream>>>(wv, wqkvb + 2097152, 262144);
    cvt4<<<1024, 256, 0, stream>>>(wo, wob, 262144);
    cvt4<<<4096, 256, 0, stream>>>(w1, w1b, 1048576);
    cvt4<<<4096, 256, 0, stream>>>(w2, w2b, 1048576);
    concat3<<<12, 256, 0, stream>>>(bq, bk, bv, bqkv);

    const dim3 blk(256);
    // QKV: (4096 x 3072) = xb @ wqkv^T
    gemm_bt<<<dim3(3072 / BN, NROWS / BM), blk, 0, stream>>>(
        xb, wqkvb, bqkv, nullptr, qkvb, 1024, 3072, 0);
    // windowed attention
    attn_win<<<65536 / 4, blk, 0, stream>>>(qkvb, rel, attnb);
    // z = attn @ wo^T + bo
    gemm_bt<<<dim3(1024 / BN, NROWS / BM), blk, 0, stream>>>(
        attnb, wob, bo, z, nullptr, 1024, 1024, 0);
    // x1 = LN(src + z)
    ln_fuse<<<NROWS / 4, blk, 0, stream>>>(src, nullptr, z, g1, be1, nullptr, x1b);
    // ff1 = relu(x1 @ w1^T + b1)
    gemm_bt<<<dim3(4096 / BN, NROWS / BM), blk, 0, stream>>>(
        x1b, w1b, b1, nullptr, ff1b, 1024, 4096, 1);
    // ff2 = ff1 @ w2^T + b2
    gemm_bt<<<dim3(1024 / BN, NROWS / BM), blk, 0, stream>>>(
        ff1b, w2b, b2, ff2, nullptr, 4096, 1024, 0);
    // out = LN(x1 + ff2)
    ln_fuse<<<NROWS / 4, blk, 0, stream>>>(nullptr, x1b, ff2, g2, be2, out, nullptr);
}

// Round 2
// 364.230 us; speedup vs baseline: 1.6691x; 1.6691x over previous
//
#include <hip/hip_runtime.h>

// ============================================================================
// ETC layer: windowed rel-pos attention + FFN, bf16 MFMA GEMMs on gfx950
//   B=2 S=2048 D_MODEL=1024 NHEAD=16 DHEAD=64 DFF=4096 R=25 W=51 K=5
// ============================================================================

#define D_MODEL 1024
#define SEQ     2048
#define NROWS   4096      // B*S
#define WIN     51
#define RAD     25

typedef __attribute__((ext_vector_type(8))) __bf16 bf16x8;
typedef __attribute__((ext_vector_type(4))) float  floatx4;

__device__ __forceinline__ unsigned short f2bf(float x) {
    unsigned u = __float_as_uint(x);
    unsigned r = u + 0x7fffu + ((u >> 16) & 1u);
    return (unsigned short)(r >> 16);
}
__device__ __forceinline__ float bf2f(unsigned short h) {
    return __uint_as_float(((unsigned)h) << 16);
}

// ---------------------------------------------------------------------------
__global__ __launch_bounds__(256) void cvt4(const float* __restrict__ in,
                                            unsigned short* __restrict__ out,
                                            int n4) {
    int i = blockIdx.x * 256 + threadIdx.x;
    if (i >= n4) return;
    float4 f = ((const float4*)in)[i];
    ushort4 u;
    u.x = f2bf(f.x); u.y = f2bf(f.y); u.z = f2bf(f.z); u.w = f2bf(f.w);
    ((ushort4*)out)[i] = u;
}

__global__ __launch_bounds__(256) void concat3(const float* __restrict__ a,
                                               const float* __restrict__ b,
                                               const float* __restrict__ c,
                                               float* __restrict__ out) {
    int i = blockIdx.x * 256 + threadIdx.x;   // 3072 total
    if (i >= 3072) return;
    float v = (i < 1024) ? a[i] : (i < 2048 ? b[i - 1024] : c[i - 2048]);
    out[i] = v;
}

// ---------------------------------------------------------------------------
// GEMM  C[M,N] = A[M,K] @ W[N,K]^T + bias   (bf16 in, fp32 acc)  [unchanged]
// ---------------------------------------------------------------------------
#define BM 128
#define BN 128
#define BK 32

__global__ __launch_bounds__(256, 2)
void gemm_bt(const unsigned short* __restrict__ A,
             const unsigned short* __restrict__ Wt,
             const float* __restrict__ bias,
             float* __restrict__ Cf,
             unsigned short* __restrict__ Cb,
             int K, int ldc, int relu)
{
    __shared__ __attribute__((aligned(16))) unsigned short As[BM * BK];
    __shared__ __attribute__((aligned(16))) unsigned short Bs[BN * BK];

    const int tid  = threadIdx.x;
    const int lane = tid & 63;
    const int wave = tid >> 6;
    const int bm = blockIdx.y * BM;
    const int bn = blockIdx.x * BN;
    const int wm = (wave >> 1) * 64;
    const int wn = (wave & 1) * 64;

    const int srow = tid >> 2;
    const int scol = (tid & 3) * 8;
    const unsigned short* Ag0 = A  + (size_t)(bm + srow) * K + scol;
    const unsigned short* Ag1 = Ag0 + (size_t)64 * K;
    const unsigned short* Wg0 = Wt + (size_t)(bn + srow) * K + scol;
    const unsigned short* Wg1 = Wg0 + (size_t)64 * K;

    const int fm = lane & 15;
    const int fk = (lane >> 4) * 8;

    floatx4 acc[4][4] = {};

    for (int k0 = 0; k0 < K; k0 += BK) {
        uint4 a0 = *(const uint4*)(Ag0 + k0);
        uint4 a1 = *(const uint4*)(Ag1 + k0);
        uint4 b0 = *(const uint4*)(Wg0 + k0);
        uint4 b1 = *(const uint4*)(Wg1 + k0);
        __syncthreads();
        *(uint4*)(As + srow * BK + scol)        = a0;
        *(uint4*)(As + (64 + srow) * BK + scol) = a1;
        *(uint4*)(Bs + srow * BK + scol)        = b0;
        *(uint4*)(Bs + (64 + srow) * BK + scol) = b1;
        __syncthreads();

        bf16x8 af[4], bf[4];
        #pragma unroll
        for (int i = 0; i < 4; i++)
            af[i] = *(const bf16x8*)(As + (wm + i * 16 + fm) * BK + fk);
        #pragma unroll
        for (int j = 0; j < 4; j++)
            bf[j] = *(const bf16x8*)(Bs + (wn + j * 16 + fm) * BK + fk);
        #pragma unroll
        for (int i = 0; i < 4; i++)
            #pragma unroll
            for (int j = 0; j < 4; j++)
                acc[i][j] = __builtin_amdgcn_mfma_f32_16x16x32_bf16(
                    af[i], bf[j], acc[i][j], 0, 0, 0);
    }

    const int r0 = bm + wm + (lane >> 4) * 4;
    const int c0 = bn + wn + (lane & 15);
    #pragma unroll
    for (int i = 0; i < 4; i++) {
        #pragma unroll
        for (int j = 0; j < 4; j++) {
            const int col = c0 + j * 16;
            const float bv = bias[col];
            #pragma unroll
            for (int r = 0; r < 4; r++) {
                const int row = r0 + i * 16 + r;
                float v = acc[i][j][r] + bv;
                if (relu) v = fmaxf(v, 0.0f);
                if (Cf) Cf[(size_t)row * ldc + col] = v;
                if (Cb) Cb[(size_t)row * ldc + col] = f2bf(v);
            }
        }
    }
}

// ---------------------------------------------------------------------------
// Banded MFMA windowed attention.
// Block = (b, h, 64-query tile). 4 waves; wave w owns queries [s0+16w, +16).
// Key band staged: tile key index t -> abs key s0 - 25 + t, t in [0,128).
// Wave w's score cols c in [0,80) map to tile key 16w + c.
// LDS strides padded for bank-conflict freedom (72 / 104 / 168 elems).
// ---------------------------------------------------------------------------
__global__ __launch_bounds__(256, 2)
void attn_mfma(const unsigned short* __restrict__ qkv,   // (B*S) x 3072 bf16
               const float* __restrict__ rel,            // 11 x 64 fp32
               unsigned short* __restrict__ attnb)       // (B*S) x 1024 bf16
{
    __shared__ __attribute__((aligned(16))) unsigned short Qs[64 * 72];
    __shared__ __attribute__((aligned(16))) unsigned short Ks[128 * 72];
    __shared__ __attribute__((aligned(16))) unsigned short Vt[64 * 168];
    __shared__ __attribute__((aligned(16))) unsigned short Rs[16 * 72];
    __shared__ __attribute__((aligned(16))) unsigned short Pl[4 * 16 * 104];
    __shared__ float Qrl[4 * 16 * 12];

    const int t   = threadIdx.x;
    const int blk = blockIdx.x;          // ((b*16 + h)*32 + st)
    const int st  = blk & 31;
    const int h   = (blk >> 5) & 15;
    const int b   = blk >> 9;
    const int s0  = st << 6;
    const int brow0 = b * SEQ;

    // ---- staging ----
    const int trow = t >> 3;             // 0..31
    const int tc   = (t & 7) * 8;        // 0,8,..,56 (elems)
    const uint4 z4 = make_uint4(0, 0, 0, 0);

    #pragma unroll
    for (int p = 0; p < 2; p++) {        // Q: 64 rows x 64 cols
        int r = trow + p * 32;
        uint4 v = *(const uint4*)(qkv + (size_t)(brow0 + s0 + r) * 3072 + h * 64 + tc);
        *(uint4*)(Qs + r * 72 + tc) = v;
    }
    #pragma unroll
    for (int p = 0; p < 4; p++) {        // K + V(transposed): 128 band rows
        int kr = trow + p * 32;
        int ka = s0 - 25 + kr;
        bool in = (ka >= 0) & (ka < SEQ);
        uint4 kv = z4, vv = z4;
        if (in) {
            kv = *(const uint4*)(qkv + (size_t)(brow0 + ka) * 3072 + 1024 + h * 64 + tc);
            vv = *(const uint4*)(qkv + (size_t)(brow0 + ka) * 3072 + 2048 + h * 64 + tc);
        }
        *(uint4*)(Ks + kr * 72 + tc) = kv;
        const unsigned short* e = (const unsigned short*)&vv;
        #pragma unroll
        for (int j = 0; j < 8; j++)
            Vt[(tc + j) * 168 + kr] = e[j];
    }
    // rel_emb -> bf16, rows 11..15 zero
    if (t < 176) {
        float4 f = ((const float4*)rel)[t];
        int fi = t * 4, rr = fi >> 6, cc = fi & 63;
        ushort4 u;
        u.x = f2bf(f.x); u.y = f2bf(f.y); u.z = f2bf(f.z); u.w = f2bf(f.w);
        *(ushort4*)(Rs + rr * 72 + cc) = u;
    } else {
        int fi = 704 + (t - 176) * 4, rr = fi >> 6, cc = fi & 63;
        *(ushort4*)(Rs + rr * 72 + cc) = make_ushort4(0, 0, 0, 0);
    }
    // zero P pad cols [80,96)
    {
        int n = t * 4, w2 = n >> 8, rem = n & 255, rr = rem >> 4, cc = 80 + (rem & 15);
        *(ushort4*)(Pl + w2 * (16 * 104) + rr * 104 + cc) = make_ushort4(0, 0, 0, 0);
    }
    // zero Vt tail cols [128,168) (read up to 143 by wave 3, must not be NaN)
    for (int idx = t; idx < 320; idx += 256) {
        int r = idx / 5, cchunk = idx % 5;
        *(uint4*)(Vt + r * 168 + 128 + cchunk * 8) = z4;
    }
    __syncthreads();

    // ---- compute (per wave) ----
    const int wave = t >> 6;
    const int lane = t & 63;
    const int fm   = lane & 15;
    const int fk8  = (lane >> 4) * 8;
    const int S0w  = s0 + wave * 16;     // wave's first query (block-rel + s0)
    unsigned short* Plw = Pl + wave * (16 * 104);
    float* Ql = Qrl + wave * (16 * 12);

    bf16x8 qa0 = *(const bf16x8*)(Qs + (wave * 16 + fm) * 72 + fk8);
    bf16x8 qa1 = *(const bf16x8*)(Qs + (wave * 16 + fm) * 72 + fk8 + 32);

    floatx4 Sc[5];
    #pragma unroll
    for (int nt = 0; nt < 5; nt++) {
        bf16x8 kb0 = *(const bf16x8*)(Ks + (wave * 16 + nt * 16 + fm) * 72 + fk8);
        bf16x8 kb1 = *(const bf16x8*)(Ks + (wave * 16 + nt * 16 + fm) * 72 + fk8 + 32);
        floatx4 acc = {0.f, 0.f, 0.f, 0.f};
        acc = __builtin_amdgcn_mfma_f32_16x16x32_bf16(qa0, kb0, acc, 0, 0, 0);
        acc = __builtin_amdgcn_mfma_f32_16x16x32_bf16(qa1, kb1, acc, 0, 0, 0);
        Sc[nt] = acc;
    }
    {   // q . rel^T  (cols 0..10 useful)
        bf16x8 rb0 = *(const bf16x8*)(Rs + fm * 72 + fk8);
        bf16x8 rb1 = *(const bf16x8*)(Rs + fm * 72 + fk8 + 32);
        floatx4 qr = {0.f, 0.f, 0.f, 0.f};
        qr = __builtin_amdgcn_mfma_f32_16x16x32_bf16(qa0, rb0, qr, 0, 0, 0);
        qr = __builtin_amdgcn_mfma_f32_16x16x32_bf16(qa1, rb1, qr, 0, 0, 0);
        if (fm < 12) {
            #pragma unroll
            for (int reg = 0; reg < 4; reg++)
                Ql[((lane >> 4) * 4 + reg) * 12 + fm] = qr[reg];
        }
    }

    // mask + rel + softmax (normalization deferred via inv[])
    float inv[4];
    const int iq0 = (lane >> 4) * 4;
    #pragma unroll
    for (int reg = 0; reg < 4; reg++) {
        const int i = iq0 + reg;         // wave-local query row
        float sc[5];
        float mx = -1e30f;
        #pragma unroll
        for (int nt = 0; nt < 5; nt++) {
            int c   = nt * 16 + fm;      // wave-local score col
            int off = c - 25 - i;        // key - query offset
            int ka  = S0w - 25 + c;      // absolute key (block batch-rel)
            bool valid = (off >= -RAD) & (off <= RAD) & (ka >= 0) & (ka < SEQ);
            int rid = min(max(off, -5), 5) + 5;
            float v = valid ? (Sc[nt][reg] + Ql[i * 12 + rid]) * 0.125f : -1e30f;
            sc[nt] = v;
            mx = fmaxf(mx, v);
        }
        #pragma unroll
        for (int o = 1; o < 16; o <<= 1) mx = fmaxf(mx, __shfl_xor(mx, o));
        float sum = 0.f;
        #pragma unroll
        for (int nt = 0; nt < 5; nt++) {
            float e = __expf(sc[nt] - mx);
            sum += e;
            Plw[i * 104 + nt * 16 + fm] = f2bf(e);
        }
        #pragma unroll
        for (int o = 1; o < 16; o <<= 1) sum += __shfl_xor(sum, o);
        inv[reg] = 1.0f / sum;
    }

    // O[16][64] = P[16][96] @ Vt^T   (keys 16w .. 16w+95, pads are zero-P)
    floatx4 O[4] = {};
    #pragma unroll
    for (int kc = 0; kc < 3; kc++) {
        bf16x8 pa = *(const bf16x8*)(Plw + fm * 104 + fk8 + kc * 32);
        #pragma unroll
        for (int nt = 0; nt < 4; nt++) {
            bf16x8 vb = *(const bf16x8*)(Vt + (nt * 16 + fm) * 168 + wave * 16 + fk8 + kc * 32);
            O[nt] = __builtin_amdgcn_mfma_f32_16x16x32_bf16(pa, vb, O[nt], 0, 0, 0);
        }
    }

    #pragma unroll
    for (int nt = 0; nt < 4; nt++) {
        const int d = nt * 16 + fm;
        #pragma unroll
        for (int reg = 0; reg < 4; reg++) {
            const int i = iq0 + reg;
            attnb[(size_t)(brow0 + S0w + i) * 1024 + h * 64 + d] = f2bf(O[nt][reg] * inv[reg]);
        }
    }
}

// ---------------------------------------------------------------------------
// Fused residual + LayerNorm (unchanged)
// ---------------------------------------------------------------------------
__global__ __launch_bounds__(256)
void ln_fuse(const float* __restrict__ af,
             const unsigned short* __restrict__ ab,
             const float* __restrict__ bres,
             const float* __restrict__ gamma,
             const float* __restrict__ beta,
             float* __restrict__ outf,
             unsigned short* __restrict__ outb)
{
    const int wave = threadIdx.x >> 6;
    const int lane = threadIdx.x & 63;
    const int row = blockIdx.x * 4 + wave;
    const size_t base = (size_t)row * D_MODEL;

    float x[16];
    float sum = 0.0f, sq = 0.0f;
    #pragma unroll
    for (int i = 0; i < 4; i++) {
        const int c4 = lane + i * 64;
        float4 vb = ((const float4*)(bres + base))[c4];
        float4 va;
        if (af) {
            va = ((const float4*)(af + base))[c4];
        } else {
            ushort4 ua = ((const ushort4*)(ab + base))[c4];
            va.x = bf2f(ua.x); va.y = bf2f(ua.y); va.z = bf2f(ua.z); va.w = bf2f(ua.w);
        }
        float e0 = va.x + vb.x, e1 = va.y + vb.y, e2 = va.z + vb.z, e3 = va.w + vb.w;
        x[i*4+0] = e0; x[i*4+1] = e1; x[i*4+2] = e2; x[i*4+3] = e3;
        sum += e0 + e1 + e2 + e3;
        sq  += e0*e0 + e1*e1 + e2*e2 + e3*e3;
    }
    #pragma unroll
    for (int off = 32; off > 0; off >>= 1) {
        sum += __shfl_xor(sum, off);
        sq  += __shfl_xor(sq,  off);
    }
    const float mean = sum * (1.0f / 1024.0f);
    const float var  = sq  * (1.0f / 1024.0f) - mean * mean;
    const float rs   = rsqrtf(var + 1e-5f);

    #pragma unroll
    for (int i = 0; i < 4; i++) {
        const int c4 = lane + i * 64;
        float4 g4 = ((const float4*)gamma)[c4];
        float4 b4 = ((const float4*)beta)[c4];
        float4 o;
        o.x = (x[i*4+0] - mean) * rs * g4.x + b4.x;
        o.y = (x[i*4+1] - mean) * rs * g4.y + b4.y;
        o.z = (x[i*4+2] - mean) * rs * g4.z + b4.z;
        o.w = (x[i*4+3] - mean) * rs * g4.w + b4.w;
        if (outf) ((float4*)(outf + base))[c4] = o;
        if (outb) {
            ushort4 u;
            u.x = f2bf(o.x); u.y = f2bf(o.y); u.z = f2bf(o.z); u.w = f2bf(o.w);
            ((ushort4*)(outb + base))[c4] = u;
        }
    }
}

// ---------------------------------------------------------------------------
extern "C" void kernel_launch(void* const* d_in, const int* in_sizes, int n_in,
                              void* d_out, int out_size, void* d_ws, size_t ws_size,
                              hipStream_t stream)
{
    const float* src = (const float*)d_in[0];
    const float* wq  = (const float*)d_in[1];
    const float* bq  = (const float*)d_in[2];
    const float* wk  = (const float*)d_in[3];
    const float* bk  = (const float*)d_in[4];
    const float* wv  = (const float*)d_in[5];
    const float* bv  = (const float*)d_in[6];
    const float* wo  = (const float*)d_in[7];
    const float* bo  = (const float*)d_in[8];
    const float* rel = (const float*)d_in[9];
    const float* w1  = (const float*)d_in[10];
    const float* b1  = (const float*)d_in[11];
    const float* w2  = (const float*)d_in[12];
    const float* b2  = (const float*)d_in[13];
    const float* g1  = (const float*)d_in[14];
    const float* be1 = (const float*)d_in[15];
    const float* g2  = (const float*)d_in[16];
    const float* be2 = (const float*)d_in[17];
    float* out = (float*)d_out;

    char* ws = (char*)d_ws;
    const size_t MB = 1048576;
    unsigned short* wqkvb = (unsigned short*)(ws + 0);        //  6 MB
    unsigned short* wob   = (unsigned short*)(ws + 6  * MB);  //  2 MB
    unsigned short* w1b   = (unsigned short*)(ws + 8  * MB);  //  8 MB
    unsigned short* w2b   = (unsigned short*)(ws + 16 * MB);  //  8 MB
    float*          bqkv  = (float*)         (ws + 24 * MB);  // 12 KB
    unsigned short* xb    = (unsigned short*)(ws + 25 * MB);  //  8 MB (dead after QKV)
    unsigned short* attnb = (unsigned short*)(ws + 25 * MB);  //  reuse xb
    unsigned short* qkvb  = (unsigned short*)(ws + 33 * MB);  // 24 MB (dead after attn)
    unsigned short* ff1b  = (unsigned short*)(ws + 33 * MB);  // 32 MB, reuse
    float*          z     = (float*)         (ws + 65 * MB);  // 16 MB (dead after LN1)
    float*          ff2   = (float*)         (ws + 65 * MB);  //  reuse z
    unsigned short* x1b   = (unsigned short*)(ws + 81 * MB);  //  8 MB

    cvt4<<<4096, 256, 0, stream>>>(src, xb, 1048576);
    cvt4<<<1024, 256, 0, stream>>>(wq, wqkvb,           262144);
    cvt4<<<1024, 256, 0, stream>>>(wk, wqkvb + 1048576, 262144);
    cvt4<<<1024, 256, 0, stream>>>(wv, wqkvb + 2097152, 262144);
    cvt4<<<1024, 256, 0, stream>>>(wo, wob, 262144);
    cvt4<<<4096, 256, 0, stream>>>(w1, w1b, 1048576);
    cvt4<<<4096, 256, 0, stream>>>(w2, w2b, 1048576);
    concat3<<<12, 256, 0, stream>>>(bq, bk, bv, bqkv);

    const dim3 blk(256);
    gemm_bt<<<dim3(3072 / BN, NROWS / BM), blk, 0, stream>>>(
        xb, wqkvb, bqkv, nullptr, qkvb, 1024, 3072, 0);
    attn_mfma<<<1024, blk, 0, stream>>>(qkvb, rel, attnb);
    gemm_bt<<<dim3(1024 / BN, NROWS / BM), blk, 0, stream>>>(
        attnb, wob, bo, z, nullptr, 1024, 1024, 0);
    ln_fuse<<<NROWS / 4, blk, 0, stream>>>(src, nullptr, z, g1, be1, nullptr, x1b);
    gemm_bt<<<dim3(4096 / BN, NROWS / BM), blk, 0, stream>>>(
        x1b, w1b, b1, nullptr, ff1b, 1024, 4096, 1);
    gemm_bt<<<dim3(1024 / BN, NROWS / BM), blk, 0, stream>>>(
        ff1b, w2b, b2, ff2, nullptr, 4096, 1024, 0);
    ln_fuse<<<NROWS / 4, blk, 0, stream>>>(nullptr, x1b, ff2, g2, be2, out, nullptr);
}